// Round 1
// baseline (254.682 us; speedup 1.0000x reference)
//
#include <hip/hip_runtime.h>
#include <math.h>

#define BLOCK 256

__device__ __forceinline__ float waveRedF(float v) {
#pragma unroll
    for (int o = 32; o > 0; o >>= 1) v += __shfl_down(v, o, 64);
    return v;
}
__device__ __forceinline__ unsigned waveRedU(unsigned v) {
#pragma unroll
    for (int o = 32; o > 0; o >>= 1) v += __shfl_down(v, o, 64);
    return v;
}

__device__ __forceinline__ void elem(float p, float t, float& bce,
                                     unsigned& tp, unsigned& tn,
                                     unsigned& gp, unsigned& gn) {
    // replace NaN/Inf with 0 (matches reference)
    p = __builtin_isfinite(p) ? p : 0.0f;
    float lp = fmaxf(__logf(p), -100.0f);          // log(0) -> -inf -> clamp -100
    float lq = fmaxf(__logf(1.0f - p), -100.0f);   // == log1p(-p) in fp32 (Sterbenz)
    bce -= t * lp + (1.0f - t) * lq;
    bool tb = t > 0.0f;
    bool pb = p > 0.5f;
    gp += (unsigned)tb;
    gn += (unsigned)(!tb);
    tp += (unsigned)(pb && tb);
    tn += (unsigned)(!pb && !tb);
}

__global__ __launch_bounds__(BLOCK) void rowKernel(
    const float* __restrict__ pred, const float* __restrict__ truth,
    const int* __restrict__ lengths, int B, int L,
    float* __restrict__ lossPart, unsigned* __restrict__ cntPart) {
    const int row = blockIdx.x;
    const int len = lengths[row];

    float bce = 0.0f;
    unsigned tp = 0, tn = 0, gp = 0, gn = 0;

    if (len > 0) {
        const float* pr = pred + (size_t)row * L;
        const float* tr = truth + (size_t)row * L;
        const float4* pv = (const float4*)pr;
        const float4* tv = (const float4*)tr;
        const int nvec = len >> 2;
        for (int v = threadIdx.x; v < nvec; v += BLOCK) {
            float4 p4 = pv[v];
            float4 t4 = tv[v];
            elem(p4.x, t4.x, bce, tp, tn, gp, gn);
            elem(p4.y, t4.y, bce, tp, tn, gp, gn);
            elem(p4.z, t4.z, bce, tp, tn, gp, gn);
            elem(p4.w, t4.w, bce, tp, tn, gp, gn);
        }
        const int base = nvec << 2;
        const int tail = len - base;
        if ((int)threadIdx.x < tail) {
            float p = pr[base + threadIdx.x];
            float t = tr[base + threadIdx.x];
            elem(p, t, bce, tp, tn, gp, gn);
        }
    }

    // wave reduce (64-wide), then LDS across the 4 waves
    bce = waveRedF(bce);
    tp = waveRedU(tp); tn = waveRedU(tn);
    gp = waveRedU(gp); gn = waveRedU(gn);

    __shared__ float sf[BLOCK / 64];
    __shared__ unsigned su[4][BLOCK / 64];
    const int wid = threadIdx.x >> 6;
    const int lane = threadIdx.x & 63;
    if (lane == 0) {
        sf[wid] = bce;
        su[0][wid] = tp; su[1][wid] = tn; su[2][wid] = gp; su[3][wid] = gn;
    }
    __syncthreads();
    if (threadIdx.x == 0) {
        float bsum = 0.0f;
        unsigned ctp = 0, ctn = 0, cgp = 0, cgn = 0;
#pragma unroll
        for (int w = 0; w < BLOCK / 64; w++) {
            bsum += sf[w];
            ctp += su[0][w]; ctn += su[1][w]; cgp += su[2][w]; cgn += su[3][w];
        }
        lossPart[row] = (len > 0) ? (bsum / (float)len) : 0.0f;
        cntPart[row]           = ctp;
        cntPart[B + row]       = ctn;
        cntPart[2 * B + row]   = cgp;
        cntPart[3 * B + row]   = cgn;
    }
}

__global__ __launch_bounds__(BLOCK) void finalKernel(
    const float* __restrict__ lossPart, const unsigned* __restrict__ cntPart,
    int B, float* __restrict__ out) {
    float ls = 0.0f;
    unsigned tp = 0, tn = 0, gp = 0, gn = 0;
    for (int i = threadIdx.x; i < B; i += BLOCK) {
        ls += lossPart[i];
        tp += cntPart[i];
        tn += cntPart[B + i];
        gp += cntPart[2 * B + i];
        gn += cntPart[3 * B + i];
    }
    ls = waveRedF(ls);
    tp = waveRedU(tp); tn = waveRedU(tn);
    gp = waveRedU(gp); gn = waveRedU(gn);

    __shared__ float sf[BLOCK / 64];
    __shared__ unsigned su[4][BLOCK / 64];
    const int wid = threadIdx.x >> 6;
    const int lane = threadIdx.x & 63;
    if (lane == 0) {
        sf[wid] = ls;
        su[0][wid] = tp; su[1][wid] = tn; su[2][wid] = gp; su[3][wid] = gn;
    }
    __syncthreads();
    if (threadIdx.x == 0) {
        float bsum = 0.0f;
        unsigned ctp = 0, ctn = 0, cgp = 0, cgn = 0;
#pragma unroll
        for (int w = 0; w < BLOCK / 64; w++) {
            bsum += sf[w];
            ctp += su[0][w]; ctn += su[1][w]; cgp += su[2][w]; cgn += su[3][w];
        }
        if (cgp == 0) cgp = 1;
        if (cgn == 0) cgn = 1;
        out[0] = bsum / (float)B;
        out[1] = ((float)ctp / (float)cgp) * ((float)ctn / (float)cgn);
    }
}

extern "C" void kernel_launch(void* const* d_in, const int* in_sizes, int n_in,
                              void* d_out, int out_size, void* d_ws, size_t ws_size,
                              hipStream_t stream) {
    const float* pred    = (const float*)d_in[0];
    const float* truth   = (const float*)d_in[1];
    const int*   lengths = (const int*)d_in[2];
    const int B = in_sizes[2];
    const int L = in_sizes[0] / B;

    float*    lossPart = (float*)d_ws;
    unsigned* cntPart  = (unsigned*)((char*)d_ws + (size_t)B * sizeof(float));

    rowKernel<<<B, BLOCK, 0, stream>>>(pred, truth, lengths, B, L, lossPart, cntPart);
    finalKernel<<<1, BLOCK, 0, stream>>>(lossPart, cntPart, B, (float*)d_out);
}